// Round 2
// baseline (694.292 us; speedup 1.0000x reference)
//
#include <hip/hip_runtime.h>
#include <stdint.h>
#include <stddef.h>

#define BM 128
#define BN 128
#define BK 128          // dense A k-chunk = 8 sparsity blocks
#define PACK_CAP 36864  // packed block capacity (exact count is 32768; cushion)

typedef __bf16 bf16x8 __attribute__((ext_vector_type(8)));
typedef float floatx4 __attribute__((ext_vector_type(4)));

// round-to-nearest-even f32 -> bf16 bits
__device__ inline unsigned short f2bf(float f) {
    union { float f; unsigned int u; } v; v.f = f;
    unsigned int u = v.u;
    return (unsigned short)((u + 0x7fffu + ((u >> 16) & 1u)) >> 16);
}

__global__ void cvt_f32_to_bf16(const float* __restrict__ in,
                                unsigned short* __restrict__ out, int n4) {
    int i = blockIdx.x * blockDim.x + threadIdx.x;
    int stride = gridDim.x * blockDim.x;
    for (int idx = i; idx < n4; idx += stride) {
        float4 f = ((const float4*)in)[idx];
        ushort4 o;
        o.x = f2bf(f.x); o.y = f2bf(f.y); o.z = f2bf(f.z); o.w = f2bf(f.w);
        ((ushort4*)out)[idx] = o;
    }
}

// Per block-row (16 rows of W): detect nonzero 16x16 blocks, write per-chunk
// 8-bit masks and local (within-row) exclusive base counts, and row nnz.
// Block-row 0 also zeroes the reserved zero-block at packedZ[0..255].
__global__ void w_scan(const float* __restrict__ W,
                       unsigned int* __restrict__ masks,
                       unsigned int* __restrict__ bases,
                       unsigned int* __restrict__ nnz,
                       unsigned short* __restrict__ packedZ,
                       int K) {
    __shared__ unsigned int flag[256];
    __shared__ unsigned int ccnt[32];
    const int nb = blockIdx.x, t = threadIdx.x;
    flag[t] = 0;
    __syncthreads();
    const float* row0 = W + (size_t)nb * 16 * K;
    const int it_n = K / 1024;
    for (int r = 0; r < 16; ++r) {
        const float4* rp = (const float4*)(row0 + (size_t)r * K);
        for (int it = 0; it < it_n; ++it) {
            int c4 = it * 256 + t;               // float4 index; col = c4*4
            float4 f = rp[c4];
            if (f.x != 0.f || f.y != 0.f || f.z != 0.f || f.w != 0.f)
                atomicOr(&flag[c4 >> 2], 1u);    // block = col/16 = c4/4
        }
    }
    __syncthreads();
    if (t < 32) {
        unsigned m = 0;
        for (int b = 0; b < 8; ++b) m |= (flag[t * 8 + b] ? 1u : 0u) << b;
        masks[nb * 32 + t] = m;
        ccnt[t] = __popc(m);
    }
    __syncthreads();
    if (t == 0) {
        unsigned s = 0;
        for (int c = 0; c < 32; ++c) { bases[nb * 32 + c] = s; s += ccnt[c]; }
        nnz[nb] = s;
    }
    if (nb == 0) packedZ[t] = 0;   // reserved zero block (256 bf16 = 512 B)
}

// Per block-row: global prefix over row nnz -> rowbase; convert+pack nonzero
// blocks to packedZ[256 + pos*256] in [n_local][k_local] (B-fragment) order;
// promote bases[] to global packed indices.
__global__ void w_pack(const float* __restrict__ W,
                       unsigned int* __restrict__ masks,
                       unsigned int* __restrict__ bases,
                       const unsigned int* __restrict__ nnz,
                       unsigned short* __restrict__ packedZ,
                       int K) {
    __shared__ int pos[256];
    __shared__ unsigned int scan[256];
    const int nb = blockIdx.x, t = threadIdx.x;
    scan[t] = nnz[t];
    __syncthreads();
    for (int off = 1; off < 256; off <<= 1) {     // Hillis-Steele inclusive
        unsigned v = (t >= off) ? scan[t - off] : 0u;
        __syncthreads();
        scan[t] += v;
        __syncthreads();
    }
    const unsigned rowbase = (nb == 0) ? 0u : scan[nb - 1];
    {
        int c = t >> 3, kl = t & 7;
        unsigned m = masks[nb * 32 + c];
        unsigned b = bases[nb * 32 + c];
        pos[t] = ((m >> kl) & 1) ? (int)(rowbase + b + __popc(m & ((1u << kl) - 1)))
                                 : -1;
    }
    __syncthreads();                               // all bases reads done
    if (t < 32) bases[nb * 32 + t] += rowbase;     // -> global packed index
    unsigned short* pk = packedZ + 256;
    const float* row0 = W + (size_t)nb * 16 * K;
    const int it_n = K / 1024;
    for (int r = 0; r < 16; ++r) {
        const float4* rp = (const float4*)(row0 + (size_t)r * K);
        for (int it = 0; it < it_n; ++it) {
            int c4 = it * 256 + t;
            int p = pos[c4 >> 2];
            if (p >= 0 && p < PACK_CAP) {
                float4 f = rp[c4];
                ushort4 o;
                o.x = f2bf(f.x); o.y = f2bf(f.y); o.z = f2bf(f.z); o.w = f2bf(f.w);
                *(ushort4*)(pk + (size_t)p * 256 + r * 16 + (c4 & 3) * 4) = o;
            }
        }
    }
}

// Block-sparse GEMM: y[m,n] = sum_k x[m,k]*W[n,k] + bias[n].
// A (x, bf16) staged densely in LDS with 16B-granule XOR swizzle; W read as
// condensed packed blocks straight from global; two k-blocks per MFMA.
__global__ void gemm_bs(const unsigned short* __restrict__ A,
                        const unsigned short* __restrict__ packedZ,
                        const unsigned int* __restrict__ masks,
                        const unsigned int* __restrict__ bases,
                        const float* __restrict__ bias,
                        float* __restrict__ C,
                        int M, int N, int K) {
    __shared__ __align__(16) unsigned short As[BM * BK];   // 32 KB, swizzled

    const int tid = threadIdx.x, lane = tid & 63, wave = tid >> 6;
    const int lr = lane & 15, lq = lane >> 4;
    const int bm = blockIdx.y * BM, bn = blockIdx.x * BN;
    const int wm = (wave >> 1) * 64, wn = (wave & 1) * 64;
    const int nb0 = (bn + wn) >> 4;

    // A staging: 8 issues/thread; phys granule G = (wave*8+i)*64 + lane holds
    // logical granule g = (G&15) ^ (row&15) of row = G>>4.
    const unsigned short* gA[8];
    const unsigned short* lA[8];
#pragma unroll
    for (int i = 0; i < 8; ++i) {
        int G = (wave * 8 + i) * 64 + lane;
        int r = G >> 4, p = G & 15;
        int g = p ^ (r & 15);
        gA[i] = A + (size_t)(bm + r) * K + g * 8;
        lA[i] = As + (size_t)G * 8;
    }

    floatx4 acc[4][4];
#pragma unroll
    for (int mi = 0; mi < 4; ++mi)
#pragma unroll
        for (int ni = 0; ni < 4; ++ni)
            acc[mi][ni] = (floatx4){0.f, 0.f, 0.f, 0.f};

    const int nchunk = K / BK;
    for (int c = 0; c < nchunk; ++c) {
#pragma unroll
        for (int i = 0; i < 8; ++i) {
            __builtin_amdgcn_global_load_lds(
                (const __attribute__((address_space(1))) void*)(gA[i]),
                (__attribute__((address_space(3))) void*)(lA[i]), 16, 0, 0);
            gA[i] += BK;
        }
        __syncthreads();

        for (int ni = 0; ni < 4; ++ni) {
            const int nb = nb0 + ni;
            unsigned m = masks[nb * 32 + c];          // wave-uniform
            if (!m) continue;
            const unsigned gb = bases[nb * 32 + c];
            unsigned j = 0;
            // peel pair 0
            int kacur = __ffs(m) - 1; m &= m - 1;
            const unsigned short* pa = packedZ + 256 + (size_t)(gb + j) * 256; ++j;
            int kbcur; const unsigned short* pb;
            if (m) { kbcur = __ffs(m) - 1; m &= m - 1;
                     pb = packedZ + 256 + (size_t)(gb + j) * 256; ++j; }
            else   { kbcur = kacur; pb = packedZ; }   // zero block
            bf16x8 bcur = *(const bf16x8*)(((lq < 2) ? pa : pb) + lr * 16 + (lq & 1) * 8);
            bool have = true;
            while (have) {
                // 1-ahead prefetch of next pair's B fragment
                bool have_n = (m != 0);
                int ka_n = kacur, kb_n = kbcur;
                bf16x8 bnext = bcur;
                if (have_n) {
                    ka_n = __ffs(m) - 1; m &= m - 1;
                    const unsigned short* pan = packedZ + 256 + (size_t)(gb + j) * 256; ++j;
                    const unsigned short* pbn;
                    if (m) { kb_n = __ffs(m) - 1; m &= m - 1;
                             pbn = packedZ + 256 + (size_t)(gb + j) * 256; ++j; }
                    else   { kb_n = ka_n; pbn = packedZ; }
                    bnext = *(const bf16x8*)(((lq < 2) ? pan : pbn) + lr * 16 + (lq & 1) * 8);
                }
                // MFMA with current pair: A k-halves gathered from swizzled LDS
                int g = (((lq < 2) ? kacur : kbcur) << 1) | (lq & 1);
                const unsigned short* ap = As + (size_t)(wm + lr) * BK + ((g ^ lr) << 3);
#pragma unroll
                for (int mi = 0; mi < 4; ++mi) {
                    bf16x8 af = *(const bf16x8*)(ap + (size_t)mi * 16 * BK);
                    acc[mi][ni] = __builtin_amdgcn_mfma_f32_16x16x32_bf16(
                        af, bcur, acc[mi][ni], 0, 0, 0);
                }
                kacur = ka_n; kbcur = kb_n; bcur = bnext; have = have_n;
            }
        }
        __syncthreads();
    }

    // epilogue: C/D layout col=lane&15, row=quad*4+reg (m89-verified)
#pragma unroll
    for (int ni = 0; ni < 4; ++ni) {
        int n = bn + wn + ni * 16 + lr;
        float bv = bias[n];
#pragma unroll
        for (int mi = 0; mi < 4; ++mi) {
            int m0 = bm + wm + mi * 16 + lq * 4;
#pragma unroll
            for (int r = 0; r < 4; ++r)
                C[(size_t)(m0 + r) * N + n] = acc[mi][ni][r] + bv;
        }
    }
}

extern "C" void kernel_launch(void* const* d_in, const int* in_sizes, int n_in,
                              void* d_out, int out_size, void* d_ws, size_t ws_size,
                              hipStream_t stream) {
    const float* x    = (const float*)d_in[0];  // [M,K]
    const float* w    = (const float*)d_in[1];  // [N,K]
    const float* bias = (const float*)d_in[2];  // [N]
    float* out = (float*)d_out;

    const int N = in_sizes[2];             // 4096
    const int K = in_sizes[1] / N;         // 4096
    const int M = in_sizes[0] / K;         // 8192
    const int NB = N / 16;                 // 256 block-rows

    char* ws = (char*)d_ws;
    size_t off = 0;
    unsigned short* xb = (unsigned short*)(ws + off);       off += (size_t)M * K * 2;
    unsigned short* packedZ = (unsigned short*)(ws + off);  off += (size_t)(PACK_CAP + 1) * 512;
    unsigned int* masks = (unsigned int*)(ws + off);        off += (size_t)NB * 32 * 4;
    unsigned int* basesp = (unsigned int*)(ws + off);       off += (size_t)NB * 32 * 4;
    unsigned int* nnzp = (unsigned int*)(ws + off);         off += (size_t)NB * 4;

    cvt_f32_to_bf16<<<4096, 256, 0, stream>>>(x, xb, (M * K) / 4);
    w_scan<<<NB, 256, 0, stream>>>(w, masks, basesp, nnzp, packedZ, K);
    w_pack<<<NB, 256, 0, stream>>>(w, masks, basesp, nnzp, packedZ, K);

    dim3 grid(N / BN, M / BM);
    gemm_bs<<<grid, 256, 0, stream>>>(xb, packedZ, masks, basesp, bias, out, M, N, K);
}

// Round 3
// 499.490 us; speedup vs baseline: 1.3900x; 1.3900x over previous
//
#include <hip/hip_runtime.h>
#include <stdint.h>
#include <stddef.h>

#define BM 128
#define BN 128
#define BK 64

typedef __bf16 bf16x8 __attribute__((ext_vector_type(8)));
typedef float floatx4 __attribute__((ext_vector_type(4)));

// round-to-nearest-even f32 -> bf16 bits
__device__ inline unsigned short f2bf(float f) {
    union { float f; unsigned int u; } v; v.f = f;
    unsigned int u = v.u;
    return (unsigned short)((u + 0x7fffu + ((u >> 16) & 1u)) >> 16);
}

__global__ void cvt_f32_to_bf16(const float* __restrict__ in,
                                unsigned short* __restrict__ out, int n4) {
    int i = blockIdx.x * blockDim.x + threadIdx.x;
    int stride = gridDim.x * blockDim.x;
    for (int idx = i; idx < n4; idx += stride) {
        float4 f = ((const float4*)in)[idx];
        ushort4 o;
        o.x = f2bf(f.x); o.y = f2bf(f.y); o.z = f2bf(f.z); o.w = f2bf(f.w);
        ((ushort4*)out)[idx] = o;
    }
}

// y[m,n] = sum_k A[m,k]*B[n,k] + bias[n]
// A: [M,K] bf16, B: [N,K] bf16 (K-major), C: [M,N] fp32.
// LDS tiles use a 16B-granule XOR swizzle: row r (8 granules of 8 bf16),
// logical granule g stored at phys granule g ^ (r&7). Staging permutes the
// GLOBAL source so global_load_lds destinations stay lane-contiguous
// (wave-uniform base + lane*16). Fragment ds_read_b128 then spreads 16 rows
// across all 32 banks at 2-way (free). Verified 0 conflicts in R2.
__global__ void gemm_bt_bias(const unsigned short* __restrict__ A,
                             const unsigned short* __restrict__ B,
                             const float* __restrict__ bias,
                             float* __restrict__ C,
                             int M, int N, int K) {
    __shared__ __align__(16) unsigned short As[BM * BK]; // 16 KB, swizzled
    __shared__ __align__(16) unsigned short Bs[BN * BK]; // 16 KB, swizzled

    const int tid  = threadIdx.x;
    const int lane = tid & 63;
    const int wave = tid >> 6;          // 0..3

    const int bm = blockIdx.y * BM;
    const int bn = blockIdx.x * BN;

    // Staging: 16 chunks of 1 KB per tile; wave w owns chunks w*4..w*4+3.
    // Chunk c, lane l -> phys granule c*64+l = (row c*8 + (l>>3), phys pg=l&7)
    // which holds logical granule g = (l&7) ^ (l>>3)  [lane-only!].
    const unsigned short* gA[4];
    const unsigned short* gB[4];
    const unsigned short* lA[4];
    const unsigned short* lB[4];
    {
        const int g = (lane & 7) ^ (lane >> 3);     // logical granule
        const int rsub = lane >> 3;                 // row within chunk
#pragma unroll
        for (int i = 0; i < 4; ++i) {
            int c = wave * 4 + i;
            int r = c * 8 + rsub;
            gA[i] = A + (size_t)(bm + r) * K + g * 8;
            gB[i] = B + (size_t)(bn + r) * K + g * 8;
            lA[i] = As + c * 512;                   // wave-uniform base
            lB[i] = Bs + c * 512;
        }
    }

    const int lr = lane & 15;           // row(A-frag) / col(B-frag) / out col
    const int lq = lane >> 4;           // quad

    const int wm = (wave >> 1) * 64;    // wave's sub-tile origin
    const int wn = (wave & 1) * 64;

    floatx4 acc[4][4];
#pragma unroll
    for (int mi = 0; mi < 4; ++mi)
#pragma unroll
        for (int ni = 0; ni < 4; ++ni)
            acc[mi][ni] = (floatx4){0.f, 0.f, 0.f, 0.f};

    for (int k0 = 0; k0 < K; k0 += BK) {
#pragma unroll
        for (int i = 0; i < 4; ++i) {
            __builtin_amdgcn_global_load_lds(
                (const __attribute__((address_space(1))) void*)(gA[i]),
                (__attribute__((address_space(3))) void*)(lA[i]), 16, 0, 0);
            __builtin_amdgcn_global_load_lds(
                (const __attribute__((address_space(1))) void*)(gB[i]),
                (__attribute__((address_space(3))) void*)(lB[i]), 16, 0, 0);
            gA[i] += BK;
            gB[i] += BK;
        }
        __syncthreads();

#pragma unroll
        for (int ks = 0; ks < 2; ++ks) {
            // phys granule offset: pg = (ks*4+lq) ^ (row&7); row&7 == lr&7
            // for all mi/ni (row bases are multiples of 16) -> hoist.
            const int pg = ((ks << 2) | lq) ^ (lr & 7);
            bf16x8 af[4], bfr[4];
#pragma unroll
            for (int mi = 0; mi < 4; ++mi)
                af[mi] = *(const bf16x8*)(As + (wm + mi * 16 + lr) * BK + pg * 8);
#pragma unroll
            for (int ni = 0; ni < 4; ++ni)
                bfr[ni] = *(const bf16x8*)(Bs + (wn + ni * 16 + lr) * BK + pg * 8);
#pragma unroll
            for (int mi = 0; mi < 4; ++mi)
#pragma unroll
                for (int ni = 0; ni < 4; ++ni)
                    acc[mi][ni] = __builtin_amdgcn_mfma_f32_16x16x32_bf16(
                        af[mi], bfr[ni], acc[mi][ni], 0, 0, 0);
        }
        __syncthreads();
    }

    // epilogue: C/D layout col=lane&15, row=quad*4+reg (m89-verified)
#pragma unroll
    for (int ni = 0; ni < 4; ++ni) {
        int n = bn + wn + ni * 16 + lr;
        float bv = bias[n];
#pragma unroll
        for (int mi = 0; mi < 4; ++mi) {
            int m0 = bm + wm + mi * 16 + lq * 4;
#pragma unroll
            for (int r = 0; r < 4; ++r) {
                C[(size_t)(m0 + r) * N + n] = acc[mi][ni][r] + bv;
            }
        }
    }
}

extern "C" void kernel_launch(void* const* d_in, const int* in_sizes, int n_in,
                              void* d_out, int out_size, void* d_ws, size_t ws_size,
                              hipStream_t stream) {
    const float* x    = (const float*)d_in[0];  // [M,K]
    const float* w    = (const float*)d_in[1];  // [N,K]
    const float* bias = (const float*)d_in[2];  // [N]
    float* out = (float*)d_out;

    const int N = in_sizes[2];             // 4096
    const int K = in_sizes[1] / N;         // 4096
    const int M = in_sizes[0] / K;         // 8192

    unsigned short* xb = (unsigned short*)d_ws;              // [M,K] bf16
    unsigned short* wb = xb + (size_t)M * K;                 // [N,K] bf16

    cvt_f32_to_bf16<<<4096, 256, 0, stream>>>(x, xb, (M * K) / 4);
    cvt_f32_to_bf16<<<4096, 256, 0, stream>>>(w, wb, (N * K) / 4);

    dim3 grid(N / BN, M / BM);
    gemm_bt_bias<<<grid, 256, 0, stream>>>(xb, wb, bias, out, M, N, K);
}